// Round 2
// baseline (11420.722 us; speedup 1.0000x reference)
//
#include <hip/hip_runtime.h>
#include <hip/hip_bf16.h>

// ---------------------------------------------------------------------------
// 2-layer LSTM, B=64 T=256 N=512 H=1024.
// R1: recurrent weights pinned in VGPRs (192/thread), c-state in registers,
// 256 WGs (all CUs), waves split K with LDS partial-sum exchange.
// ---------------------------------------------------------------------------

#define T_ 256
#define B_ 64
#define N_ 512
#define H_ 1024
#define FH_ 4096
#define NWG_SEQ 256

typedef _Float16 f16;
typedef _Float16 f16x4 __attribute__((ext_vector_type(4)));
typedef _Float16 f16x8 __attribute__((ext_vector_type(8)));
typedef float f32x4 __attribute__((ext_vector_type(4)));

template <bool V> struct BC { static constexpr bool value = V; };

__device__ __forceinline__ float sigf(float x) { return 1.f / (1.f + __expf(-x)); }
__device__ __forceinline__ float tanhf_fast(float x) { return 1.f - 2.f / (__expf(2.f * x) + 1.f); }

// ---------------------------------------------------------------------------
// init / convert kernel
// ---------------------------------------------------------------------------
__global__ __launch_bounds__(256) void init_all(
    const float* __restrict__ x, const float* __restrict__ h,
    const float* __restrict__ Wih0, const float* __restrict__ bih0, const float* __restrict__ bhh0,
    const float* __restrict__ Whh0, const float* __restrict__ Wih1, const float* __restrict__ Whh1,
    const float* __restrict__ bih1, const float* __restrict__ bhh1,
    f16* __restrict__ xT, f16* __restrict__ wih0, f16* __restrict__ whh0,
    f16* __restrict__ wih1, f16* __restrict__ whh1,
    float* __restrict__ bias0, float* __restrict__ bias1,
    f16* __restrict__ hinit, unsigned* __restrict__ bar)
{
  const int stride = gridDim.x * blockDim.x;
  const int t0 = blockIdx.x * blockDim.x + threadIdx.x;

  // x[B,T,N] -> xT[(t*B+b), N] as f16
  for (int i = t0; i < T_ * B_ * N_; i += stride) {
    int n = i & (N_ - 1);
    int tb = i >> 9;           // / N_
    int b = tb & (B_ - 1);
    int t = tb >> 6;           // / B_
    xT[i] = (f16)x[((size_t)b * T_ + t) * N_ + n];
  }
  for (int i = t0; i < FH_ * N_; i += stride) wih0[i] = (f16)Wih0[i];
  for (int i = t0; i < FH_ * H_; i += stride) {
    whh0[i] = (f16)Whh0[i];
    wih1[i] = (f16)Wih1[i];
    whh1[i] = (f16)Whh1[i];
  }
  for (int i = t0; i < FH_; i += stride) {
    bias0[i] = bih0[i] + bhh0[i];
    bias1[i] = bih1[i] + bhh1[i];
  }
  for (int i = t0; i < 2 * B_ * H_; i += stride) hinit[i] = (f16)h[i];
  if (t0 < 64) bar[t0] = 0u;
}

// ---------------------------------------------------------------------------
// GEMM: pre0T[t][col][b] = (xT @ wih0^T + bias0), stored f16 TRANSPOSED.
// M=16384 N=4096 K=512. Block = 4 waves; wave computes one 64x64 tile.
// ---------------------------------------------------------------------------
__global__ __launch_bounds__(256) void gemm_pre0(
    const f16* __restrict__ xT, const f16* __restrict__ wih0,
    const float* __restrict__ bias0, f16* __restrict__ pre0T)
{
  const int wid = threadIdx.x >> 6;
  const int lane = threadIdx.x & 63;
  const int lr = lane & 15;
  const int lkq = (lane >> 4) << 3;
  const int lrq = (lane >> 4) << 2;

  const int mt = blockIdx.x & 255;            // row tile (= t, 64 batch rows)
  const int ct = (blockIdx.x >> 8) * 4 + wid; // col tile (64 cols)
  const int row0 = mt * 64, col0 = ct * 64;

  f32x4 acc[4][4] = {};
  const f16* Abase = xT + (size_t)row0 * N_;

  #pragma unroll 2
  for (int kk = 0; kk < N_ / 32; ++kk) {
    const int k = kk * 32 + lkq;
    f16x8 a[4], b[4];
    #pragma unroll
    for (int r = 0; r < 4; ++r)
      a[r] = *(const f16x8*)(Abase + (size_t)(r * 16 + lr) * N_ + k);
    #pragma unroll
    for (int cf = 0; cf < 4; ++cf)
      b[cf] = *(const f16x8*)(wih0 + (size_t)(col0 + cf * 16 + lr) * N_ + k);
    #pragma unroll
    for (int r = 0; r < 4; ++r)
      #pragma unroll
      for (int cf = 0; cf < 4; ++cf)
        acc[r][cf] = __builtin_amdgcn_mfma_f32_16x16x32_f16(a[r], b[cf], acc[r][cf], 0, 0, 0);
  }

  // transposed store: pre0T[(mt*4096 + col)*64 + row_in_tile]
  #pragma unroll
  for (int r = 0; r < 4; ++r) {
    #pragma unroll
    for (int cf = 0; cf < 4; ++cf) {
      const int col = col0 + cf * 16 + lr;
      const float bv = bias0[col];
      f16x4 pv;
      #pragma unroll
      for (int ri = 0; ri < 4; ++ri) pv[ri] = (f16)(acc[r][cf][ri] + bv);
      *(f16x4*)(pre0T + ((size_t)mt * FH_ + col) * 64 + r * 16 + lrq) = pv;
    }
  }
}

// ---------------------------------------------------------------------------
// Grid barrier (generation = epoch index; cnt and gen on separate lines).
// ---------------------------------------------------------------------------
__device__ __forceinline__ void grid_barrier(unsigned* cnt, unsigned* gen, unsigned idx)
{
  __syncthreads();
  if (threadIdx.x == 0) {
    __threadfence();  // release
    unsigned a = __hip_atomic_fetch_add(cnt, 1u, __ATOMIC_ACQ_REL, __HIP_MEMORY_SCOPE_AGENT);
    if (a == NWG_SEQ - 1) {
      __hip_atomic_store(cnt, 0u, __ATOMIC_RELAXED, __HIP_MEMORY_SCOPE_AGENT);
      __hip_atomic_store(gen, idx + 1u, __ATOMIC_RELEASE, __HIP_MEMORY_SCOPE_AGENT);
    } else {
      while (__hip_atomic_load(gen, __ATOMIC_ACQUIRE, __HIP_MEMORY_SCOPE_AGENT) < idx + 1u)
        __builtin_amdgcn_s_sleep(2);
    }
    __threadfence();  // acquire
  }
  __syncthreads();
}

// ---------------------------------------------------------------------------
// Persistent pipelined kernel. 256 WGs x 256 threads (1 WG/CU).
//   WG tile: rows rs..rs+31 (batch), units ub..ub+7 of each of 4 gates,
//   for BOTH layers. Wave p = K-quarter. Weights live in VGPRs.
// ---------------------------------------------------------------------------
__global__ __launch_bounds__(256) void lstm_seq(
    const f16* __restrict__ pre0T, const f16* __restrict__ whh0,
    const f16* __restrict__ wih1, const f16* __restrict__ whh1,
    const float* __restrict__ bias1, const f16* __restrict__ hinit,
    const float* __restrict__ cin,
    f16* __restrict__ h0buf, f16* __restrict__ h1buf,
    float* __restrict__ out, unsigned* __restrict__ bar)
{
  __shared__ __align__(16) unsigned char ldsA[65536];   // h0 rows (swizzled)
  __shared__ __align__(16) union SMB {
    unsigned char b[65536];                             // h1 rows (swizzled)
    float exc[2][4][32][33];                            // partial-sum exchange
  } smB;

  const int tid = threadIdx.x;
  const int p = tid >> 6;          // wave = K-quarter
  const int lane = tid & 63;
  const int lr = lane & 15;
  const int lq = lane >> 4;
  const int lkq = lq << 3;
  const int lrq = lq << 2;

  const int wg = blockIdx.x;
  const int rs = (wg >> 7) << 5;   // batch-row base: 0 or 32
  const int ub = (wg & 127) << 3;  // unit base: 8 units per gate

  // ---- preload weight fragments into registers (48 x f16x8 = 192 VGPR) ----
  f16x8 l0w[2][8], l1aw[2][8], l1bw[2][8];
  #pragma unroll
  for (int cf = 0; cf < 2; ++cf) {
    const size_t wr = (size_t)((2 * cf + (lr >> 3)) * H_ + ub + (lr & 7)) * H_;
    #pragma unroll
    for (int j = 0; j < 8; ++j) {
      const int k = (p * 8 + j) * 32 + lkq;
      l0w[cf][j]  = *(const f16x8*)(whh0 + wr + k);
      l1aw[cf][j] = *(const f16x8*)(wih1 + wr + k);
      l1bw[cf][j] = *(const f16x8*)(whh1 + wr + k);
    }
  }

  // ---- per-thread cell state ----
  const int crow = tid & 31;       // cell row (batch, relative)
  const int cu = tid >> 5;         // cell unit (0..7)
  const size_t cell = (size_t)(rs + crow) * H_ + ub + cu;
  float c0 = cin[cell];
  float c1 = cin[(size_t)B_ * H_ + cell];
  float b1v[4];
  #pragma unroll
  for (int g = 0; g < 4; ++g) b1v[g] = bias1[g * H_ + ub + cu];

  float* outh = out + (size_t)B_ * T_ * H_;
  float* outc = outh + 2 * B_ * H_;

  auto body = [&](auto A0c, auto A1c, int e) {
    constexpr bool A0 = decltype(A0c)::value;
    constexpr bool A1 = decltype(A1c)::value;

    // prefetch pre0 additive term early (consumed at update)
    float pf[4];
    if (A0) {
      #pragma unroll
      for (int g = 0; g < 4; ++g)
        pf[g] = (float)pre0T[((size_t)e * FH_ + g * H_ + ub + cu) * 64 + rs + crow];
    }

    // stage h0[e-1] rows rs..rs+31 into ldsA
    {
      const f16* h0src = (e == 0) ? hinit : h0buf + (size_t)((e - 1) & 1) * (B_ * H_);
      const f16* src = h0src + (size_t)rs * H_;
      #pragma unroll
      for (int it = 0; it < 16; ++it) {
        const int ch = tid + it * 256;
        const int row = ch >> 7;
        f16x8 v = *(const f16x8*)(src + ((size_t)ch << 3));
        *(f16x8*)(&ldsA[(ch << 4) ^ ((row & 7) << 4)]) = v;
      }
    }
    if (A1) {  // stage h1[e-2]
      const f16* h1src = (e == 1) ? hinit + B_ * H_ : h1buf + (size_t)(e & 1) * (B_ * H_);
      const f16* src = h1src + (size_t)rs * H_;
      #pragma unroll
      for (int it = 0; it < 16; ++it) {
        const int ch = tid + it * 256;
        const int row = ch >> 7;
        f16x8 v = *(const f16x8*)(src + ((size_t)ch << 3));
        *(f16x8*)(&smB.b[(ch << 4) ^ ((row & 7) << 4)]) = v;
      }
    }
    __syncthreads();

    f32x4 acc0[2][2] = {};
    f32x4 acc1[2][2] = {};
    #pragma unroll
    for (int j = 0; j < 8; ++j) {
      const int k = (p * 8 + j) * 32 + lkq;
      const int r0 = lr, r1 = 16 + lr;
      f16x8 a0 = *(const f16x8*)(&ldsA[(r0 * 2048 + k * 2) ^ ((r0 & 7) << 4)]);
      f16x8 a1 = *(const f16x8*)(&ldsA[(r1 * 2048 + k * 2) ^ ((r1 & 7) << 4)]);
      if (A0) {
        #pragma unroll
        for (int cf = 0; cf < 2; ++cf) {
          acc0[cf][0] = __builtin_amdgcn_mfma_f32_16x16x32_f16(a0, l0w[cf][j], acc0[cf][0], 0, 0, 0);
          acc0[cf][1] = __builtin_amdgcn_mfma_f32_16x16x32_f16(a1, l0w[cf][j], acc0[cf][1], 0, 0, 0);
        }
      }
      if (A1) {
        #pragma unroll
        for (int cf = 0; cf < 2; ++cf) {
          acc1[cf][0] = __builtin_amdgcn_mfma_f32_16x16x32_f16(a0, l1aw[cf][j], acc1[cf][0], 0, 0, 0);
          acc1[cf][1] = __builtin_amdgcn_mfma_f32_16x16x32_f16(a1, l1aw[cf][j], acc1[cf][1], 0, 0, 0);
        }
      }
    }
    if (A1) {
      #pragma unroll
      for (int j = 0; j < 8; ++j) {
        const int k = (p * 8 + j) * 32 + lkq;
        const int r0 = lr, r1 = 16 + lr;
        f16x8 a0 = *(const f16x8*)(&smB.b[(r0 * 2048 + k * 2) ^ ((r0 & 7) << 4)]);
        f16x8 a1 = *(const f16x8*)(&smB.b[(r1 * 2048 + k * 2) ^ ((r1 & 7) << 4)]);
        #pragma unroll
        for (int cf = 0; cf < 2; ++cf) {
          acc1[cf][0] = __builtin_amdgcn_mfma_f32_16x16x32_f16(a0, l1bw[cf][j], acc1[cf][0], 0, 0, 0);
          acc1[cf][1] = __builtin_amdgcn_mfma_f32_16x16x32_f16(a1, l1bw[cf][j], acc1[cf][1], 0, 0, 0);
        }
      }
    }
    __syncthreads();

    // partial-sum exchange (overlays smB staging area)
    #pragma unroll
    for (int cf = 0; cf < 2; ++cf)
      #pragma unroll
      for (int rf = 0; rf < 2; ++rf)
        #pragma unroll
        for (int ri = 0; ri < 4; ++ri) {
          if (A0) smB.exc[0][p][rf * 16 + lrq + ri][cf * 16 + lr] = acc0[cf][rf][ri];
          if (A1) smB.exc[1][p][rf * 16 + lrq + ri][cf * 16 + lr] = acc1[cf][rf][ri];
        }
    __syncthreads();

    if (A0) {
      float gv[4];
      #pragma unroll
      for (int g = 0; g < 4; ++g)
        gv[g] = smB.exc[0][0][crow][g * 8 + cu] + smB.exc[0][1][crow][g * 8 + cu]
              + smB.exc[0][2][crow][g * 8 + cu] + smB.exc[0][3][crow][g * 8 + cu] + pf[g];
      const float cn = sigf(gv[1]) * c0 + sigf(gv[0]) * tanhf_fast(gv[2]);
      const float hn = sigf(gv[3]) * tanhf_fast(cn);
      c0 = cn;
      h0buf[(size_t)(e & 1) * (B_ * H_) + cell] = (f16)hn;
      if (e == T_ - 1) { outh[cell] = hn; outc[cell] = cn; }
    }
    if (A1) {
      const int t = e - 1;
      float gv[4];
      #pragma unroll
      for (int g = 0; g < 4; ++g)
        gv[g] = smB.exc[1][0][crow][g * 8 + cu] + smB.exc[1][1][crow][g * 8 + cu]
              + smB.exc[1][2][crow][g * 8 + cu] + smB.exc[1][3][crow][g * 8 + cu] + b1v[g];
      const float cn = sigf(gv[1]) * c1 + sigf(gv[0]) * tanhf_fast(gv[2]);
      const float hn = sigf(gv[3]) * tanhf_fast(cn);
      c1 = cn;
      h1buf[(size_t)((e - 1) & 1) * (B_ * H_) + cell] = (f16)hn;
      out[(size_t)(rs + crow) * (T_ * H_) + (size_t)t * H_ + ub + cu] = hn;
      if (e == T_) { outh[(size_t)B_ * H_ + cell] = hn; outc[(size_t)B_ * H_ + cell] = cn; }
    }
  };

  body(BC<true>{}, BC<false>{}, 0);
  grid_barrier(bar, bar + 16, 0u);
  for (int e = 1; e < T_; ++e) {
    body(BC<true>{}, BC<true>{}, e);
    grid_barrier(bar, bar + 16, (unsigned)e);
  }
  body(BC<false>{}, BC<true>{}, T_);
}

// ---------------------------------------------------------------------------
extern "C" void kernel_launch(void* const* d_in, const int* in_sizes, int n_in,
                              void* d_out, int out_size, void* d_ws, size_t ws_size,
                              hipStream_t stream)
{
  const float* x    = (const float*)d_in[0];
  const float* h    = (const float*)d_in[1];
  const float* c    = (const float*)d_in[2];
  const float* Wih0 = (const float*)d_in[3];
  const float* Whh0 = (const float*)d_in[4];
  const float* bih0 = (const float*)d_in[5];
  const float* bhh0 = (const float*)d_in[6];
  const float* Wih1 = (const float*)d_in[7];
  const float* Whh1 = (const float*)d_in[8];
  const float* bih1 = (const float*)d_in[9];
  const float* bhh1 = (const float*)d_in[10];

  char* w = (char*)d_ws;
  size_t off = 0;
  auto carve = [&](size_t bytes) -> char* {
    char* p = w + off;
    off = (off + bytes + 255) & ~(size_t)255;
    return p;
  };
  f16*   pre0T = (f16*)  carve((size_t)T_ * B_ * FH_ * 2);
  f16*   xT    = (f16*)  carve((size_t)T_ * B_ * N_ * 2);
  f16*   wih0  = (f16*)  carve((size_t)FH_ * N_ * 2);
  f16*   whh0  = (f16*)  carve((size_t)FH_ * H_ * 2);
  f16*   wih1  = (f16*)  carve((size_t)FH_ * H_ * 2);
  f16*   whh1  = (f16*)  carve((size_t)FH_ * H_ * 2);
  float* bias0 = (float*)carve((size_t)FH_ * 4);
  float* bias1 = (float*)carve((size_t)FH_ * 4);
  f16*   hinit = (f16*)  carve((size_t)2 * B_ * H_ * 2);
  f16*   h0buf = (f16*)  carve((size_t)2 * B_ * H_ * 2);
  f16*   h1buf = (f16*)  carve((size_t)2 * B_ * H_ * 2);
  unsigned* bar = (unsigned*)carve(256);
  if (off > ws_size) return;

  init_all<<<2048, 256, 0, stream>>>(x, h, Wih0, bih0, bhh0, Whh0, Wih1, Whh1, bih1, bhh1,
                                     xT, wih0, whh0, wih1, whh1, bias0, bias1, hinit, bar);
  gemm_pre0<<<4096, 256, 0, stream>>>(xT, wih0, bias0, pre0T);
  lstm_seq<<<NWG_SEQ, 256, 0, stream>>>(pre0T, whh0, wih1, whh1, bias1, hinit, (const float*)c,
                                        h0buf, h1buf, (float*)d_out, bar);
}

// Round 3
// 5823.355 us; speedup vs baseline: 1.9612x; 1.9612x over previous
//
#include <hip/hip_runtime.h>
#include <hip/hip_bf16.h>

// ---------------------------------------------------------------------------
// 2-layer LSTM, B=64 T=256 N=512 H=1024.
// R2: dataflow sync. No grid barrier, no atomic RMW. Producers publish h via
// uncached (MALL-coherent) stores + per-WG flag words; consumers poll flags
// with one wave-wide uncached load, then acquire-inv and cached staging.
// Weights stay pinned in VGPRs (R1). Two independent 128-WG pods.
// ---------------------------------------------------------------------------

#define T_ 256
#define B_ 64
#define N_ 512
#define H_ 1024
#define FH_ 4096
#define NWG_SEQ 256

typedef _Float16 f16;
typedef _Float16 f16x4 __attribute__((ext_vector_type(4)));
typedef _Float16 f16x8 __attribute__((ext_vector_type(8)));
typedef float f32x4 __attribute__((ext_vector_type(4)));

template <bool V> struct BC { static constexpr bool value = V; };

__device__ __forceinline__ float sigf(float x) { return 1.f / (1.f + __expf(-x)); }
__device__ __forceinline__ float tanhf_fast(float x) { return 1.f - 2.f / (__expf(2.f * x) + 1.f); }

// uncached (agent-scope, MALL-coherent) accessors
__device__ __forceinline__ void st_u64g(unsigned long long* p, unsigned long long v) {
  __hip_atomic_store(p, v, __ATOMIC_RELAXED, __HIP_MEMORY_SCOPE_AGENT);
}
__device__ __forceinline__ unsigned long long ld_u64g(const unsigned long long* p) {
  return __hip_atomic_load(p, __ATOMIC_RELAXED, __HIP_MEMORY_SCOPE_AGENT);
}
__device__ __forceinline__ void st_u32g(unsigned* p, unsigned v) {
  __hip_atomic_store(p, v, __ATOMIC_RELAXED, __HIP_MEMORY_SCOPE_AGENT);
}
__device__ __forceinline__ void st_f32g(float* p, float v) {
  union { float f; unsigned u; } c; c.f = v;
  st_u32g((unsigned*)p, c.u);
}

// ---------------------------------------------------------------------------
// init / convert kernel
// ---------------------------------------------------------------------------
__global__ __launch_bounds__(256) void init_all(
    const float* __restrict__ x, const float* __restrict__ h,
    const float* __restrict__ Wih0, const float* __restrict__ bih0, const float* __restrict__ bhh0,
    const float* __restrict__ Whh0, const float* __restrict__ Wih1, const float* __restrict__ Whh1,
    const float* __restrict__ bih1, const float* __restrict__ bhh1,
    f16* __restrict__ xT, f16* __restrict__ wih0, f16* __restrict__ whh0,
    f16* __restrict__ wih1, f16* __restrict__ whh1,
    float* __restrict__ bias0, float* __restrict__ bias1,
    f16* __restrict__ hinit, unsigned* __restrict__ flags)
{
  const int stride = gridDim.x * blockDim.x;
  const int t0 = blockIdx.x * blockDim.x + threadIdx.x;

  for (int i = t0; i < T_ * B_ * N_; i += stride) {
    int n = i & (N_ - 1);
    int tb = i >> 9;
    int b = tb & (B_ - 1);
    int t = tb >> 6;
    xT[i] = (f16)x[((size_t)b * T_ + t) * N_ + n];
  }
  for (int i = t0; i < FH_ * N_; i += stride) wih0[i] = (f16)Wih0[i];
  for (int i = t0; i < FH_ * H_; i += stride) {
    whh0[i] = (f16)Whh0[i];
    wih1[i] = (f16)Wih1[i];
    whh1[i] = (f16)Whh1[i];
  }
  for (int i = t0; i < FH_; i += stride) {
    bias0[i] = bih0[i] + bhh0[i];
    bias1[i] = bih1[i] + bhh1[i];
  }
  for (int i = t0; i < 2 * B_ * H_; i += stride) hinit[i] = (f16)h[i];
  if (t0 < NWG_SEQ) flags[t0] = 0u;
}

// ---------------------------------------------------------------------------
// GEMM: pre0T[t][col][b] = (xT @ wih0^T + bias0), stored f16 TRANSPOSED.
// ---------------------------------------------------------------------------
__global__ __launch_bounds__(256) void gemm_pre0(
    const f16* __restrict__ xT, const f16* __restrict__ wih0,
    const float* __restrict__ bias0, f16* __restrict__ pre0T)
{
  const int wid = threadIdx.x >> 6;
  const int lane = threadIdx.x & 63;
  const int lr = lane & 15;
  const int lkq = (lane >> 4) << 3;
  const int lrq = (lane >> 4) << 2;

  const int mt = blockIdx.x & 255;
  const int ct = (blockIdx.x >> 8) * 4 + wid;
  const int row0 = mt * 64, col0 = ct * 64;

  f32x4 acc[4][4] = {};
  const f16* Abase = xT + (size_t)row0 * N_;

  #pragma unroll 2
  for (int kk = 0; kk < N_ / 32; ++kk) {
    const int k = kk * 32 + lkq;
    f16x8 a[4], b[4];
    #pragma unroll
    for (int r = 0; r < 4; ++r)
      a[r] = *(const f16x8*)(Abase + (size_t)(r * 16 + lr) * N_ + k);
    #pragma unroll
    for (int cf = 0; cf < 4; ++cf)
      b[cf] = *(const f16x8*)(wih0 + (size_t)(col0 + cf * 16 + lr) * N_ + k);
    #pragma unroll
    for (int r = 0; r < 4; ++r)
      #pragma unroll
      for (int cf = 0; cf < 4; ++cf)
        acc[r][cf] = __builtin_amdgcn_mfma_f32_16x16x32_f16(a[r], b[cf], acc[r][cf], 0, 0, 0);
  }

  #pragma unroll
  for (int r = 0; r < 4; ++r) {
    #pragma unroll
    for (int cf = 0; cf < 4; ++cf) {
      const int col = col0 + cf * 16 + lr;
      const float bv = bias0[col];
      f16x4 pv;
      #pragma unroll
      for (int ri = 0; ri < 4; ++ri) pv[ri] = (f16)(acc[r][cf][ri] + bv);
      *(f16x4*)(pre0T + ((size_t)mt * FH_ + col) * 64 + r * 16 + lrq) = pv;
    }
  }
}

// ---------------------------------------------------------------------------
// Persistent dataflow kernel. 256 WGs x 256 threads (1 WG/CU).
// Pod = 128 WGs sharing batch rows (rs). slot = wg&127. Per epoch e:
//   wait(all pod flags >= e) -> acquire-inv -> stage(cached) -> MFMA ->
//   exchange -> cell update -> uncached h/out stores -> vmcnt0 -> flag=e+1.
// ---------------------------------------------------------------------------
__global__ __launch_bounds__(256) void lstm_seq(
    const f16* __restrict__ pre0T, const f16* __restrict__ whh0,
    const f16* __restrict__ wih1, const f16* __restrict__ whh1,
    const float* __restrict__ bias1, const f16* __restrict__ hinit,
    const float* __restrict__ cin,
    f16* __restrict__ h0buf, f16* __restrict__ h1buf,
    float* __restrict__ out, unsigned* __restrict__ flags)
{
  __shared__ __align__(16) unsigned char ldsA[65536];   // h0 rows (swizzled)
  __shared__ __align__(16) union SMB {
    unsigned char b[65536];                             // h1 rows (swizzled)
    float exc[2][4][32][33];                            // partial-sum exchange
  } smB;
  __shared__ __align__(16) f16 smH[2][32][8];           // packed h outputs

  const int tid = threadIdx.x;
  const int p = tid >> 6;          // wave = K-quarter
  const int lane = tid & 63;
  const int lr = lane & 15;
  const int lq = lane >> 4;
  const int lkq = lq << 3;
  const int lrq = lq << 2;

  const int wg = blockIdx.x;
  const int pod = wg >> 7;         // 0: rows 0..31, 1: rows 32..63
  const int slot = wg & 127;
  const int rs = pod << 5;
  const int ub = slot << 3;        // unit base: 8 units per gate
  unsigned* podflags = flags + pod * 128;

  // ---- preload weight fragments into registers (48 x f16x8) ----
  f16x8 l0w[2][8], l1aw[2][8], l1bw[2][8];
  #pragma unroll
  for (int cf = 0; cf < 2; ++cf) {
    const size_t wr = (size_t)((2 * cf + (lr >> 3)) * H_ + ub + (lr & 7)) * H_;
    #pragma unroll
    for (int j = 0; j < 8; ++j) {
      const int k = (p * 8 + j) * 32 + lkq;
      l0w[cf][j]  = *(const f16x8*)(whh0 + wr + k);
      l1aw[cf][j] = *(const f16x8*)(wih1 + wr + k);
      l1bw[cf][j] = *(const f16x8*)(whh1 + wr + k);
    }
  }

  // ---- per-thread cell state ----
  const int crow = tid & 31;
  const int cu = tid >> 5;
  const size_t cell = (size_t)(rs + crow) * H_ + ub + cu;
  float c0 = cin[cell];
  float c1 = cin[(size_t)B_ * H_ + cell];
  float b1v[4];
  #pragma unroll
  for (int g = 0; g < 4; ++g) b1v[g] = bias1[g * H_ + ub + cu];

  float* outh = out + (size_t)B_ * T_ * H_;
  float* outc = outh + 2 * B_ * H_;

  auto body = [&](auto A0c, auto A1c, int e) {
    constexpr bool A0 = decltype(A0c)::value;
    constexpr bool A1 = decltype(A1c)::value;

    float pf[4];
    if (A0) {
      #pragma unroll
      for (int g = 0; g < 4; ++g)
        pf[g] = (float)pre0T[((size_t)e * FH_ + g * H_ + ub + cu) * 64 + rs + crow];
    }

    // stage h0[e-1] rows rs..rs+31 (cached loads; fresh after acquire-inv)
    {
      const f16* h0src = (e == 0) ? hinit : h0buf + (size_t)((e - 1) & 1) * (B_ * H_);
      const f16* src = h0src + (size_t)rs * H_;
      #pragma unroll
      for (int it = 0; it < 16; ++it) {
        const int ch = tid + it * 256;
        const int row = ch >> 7;
        f16x8 v = *(const f16x8*)(src + ((size_t)ch << 3));
        *(f16x8*)(&ldsA[(ch << 4) ^ ((row & 7) << 4)]) = v;
      }
    }
    if (A1) {  // stage h1[e-2]
      const f16* h1src = (e == 1) ? hinit + B_ * H_ : h1buf + (size_t)(e & 1) * (B_ * H_);
      const f16* src = h1src + (size_t)rs * H_;
      #pragma unroll
      for (int it = 0; it < 16; ++it) {
        const int ch = tid + it * 256;
        const int row = ch >> 7;
        f16x8 v = *(const f16x8*)(src + ((size_t)ch << 3));
        *(f16x8*)(&smB.b[(ch << 4) ^ ((row & 7) << 4)]) = v;
      }
    }
    __syncthreads();

    f32x4 acc0[2][2] = {};
    f32x4 acc1[2][2] = {};
    #pragma unroll
    for (int j = 0; j < 8; ++j) {
      const int k = (p * 8 + j) * 32 + lkq;
      const int r0 = lr, r1 = 16 + lr;
      f16x8 a0 = *(const f16x8*)(&ldsA[(r0 * 2048 + k * 2) ^ ((r0 & 7) << 4)]);
      f16x8 a1 = *(const f16x8*)(&ldsA[(r1 * 2048 + k * 2) ^ ((r1 & 7) << 4)]);
      if (A0) {
        #pragma unroll
        for (int cf = 0; cf < 2; ++cf) {
          acc0[cf][0] = __builtin_amdgcn_mfma_f32_16x16x32_f16(a0, l0w[cf][j], acc0[cf][0], 0, 0, 0);
          acc0[cf][1] = __builtin_amdgcn_mfma_f32_16x16x32_f16(a1, l0w[cf][j], acc0[cf][1], 0, 0, 0);
        }
      }
      if (A1) {
        #pragma unroll
        for (int cf = 0; cf < 2; ++cf) {
          acc1[cf][0] = __builtin_amdgcn_mfma_f32_16x16x32_f16(a0, l1aw[cf][j], acc1[cf][0], 0, 0, 0);
          acc1[cf][1] = __builtin_amdgcn_mfma_f32_16x16x32_f16(a1, l1aw[cf][j], acc1[cf][1], 0, 0, 0);
        }
      }
    }
    if (A1) {
      #pragma unroll
      for (int j = 0; j < 8; ++j) {
        const int k = (p * 8 + j) * 32 + lkq;
        const int r0 = lr, r1 = 16 + lr;
        f16x8 a0 = *(const f16x8*)(&smB.b[(r0 * 2048 + k * 2) ^ ((r0 & 7) << 4)]);
        f16x8 a1 = *(const f16x8*)(&smB.b[(r1 * 2048 + k * 2) ^ ((r1 & 7) << 4)]);
        #pragma unroll
        for (int cf = 0; cf < 2; ++cf) {
          acc1[cf][0] = __builtin_amdgcn_mfma_f32_16x16x32_f16(a0, l1bw[cf][j], acc1[cf][0], 0, 0, 0);
          acc1[cf][1] = __builtin_amdgcn_mfma_f32_16x16x32_f16(a1, l1bw[cf][j], acc1[cf][1], 0, 0, 0);
        }
      }
    }
    __syncthreads();

    #pragma unroll
    for (int cf = 0; cf < 2; ++cf)
      #pragma unroll
      for (int rf = 0; rf < 2; ++rf)
        #pragma unroll
        for (int ri = 0; ri < 4; ++ri) {
          if (A0) smB.exc[0][p][rf * 16 + lrq + ri][cf * 16 + lr] = acc0[cf][rf][ri];
          if (A1) smB.exc[1][p][rf * 16 + lrq + ri][cf * 16 + lr] = acc1[cf][rf][ri];
        }
    __syncthreads();

    if (A0) {
      float gv[4];
      #pragma unroll
      for (int g = 0; g < 4; ++g)
        gv[g] = smB.exc[0][0][crow][g * 8 + cu] + smB.exc[0][1][crow][g * 8 + cu]
              + smB.exc[0][2][crow][g * 8 + cu] + smB.exc[0][3][crow][g * 8 + cu] + pf[g];
      const float cn = sigf(gv[1]) * c0 + sigf(gv[0]) * tanhf_fast(gv[2]);
      const float hn = sigf(gv[3]) * tanhf_fast(cn);
      c0 = cn;
      smH[0][crow][cu] = (f16)hn;
      if (e == T_ - 1) { st_f32g(&outh[cell], hn); st_f32g(&outc[cell], cn); }
    }
    if (A1) {
      const int t = e - 1;
      float gv[4];
      #pragma unroll
      for (int g = 0; g < 4; ++g)
        gv[g] = smB.exc[1][0][crow][g * 8 + cu] + smB.exc[1][1][crow][g * 8 + cu]
              + smB.exc[1][2][crow][g * 8 + cu] + smB.exc[1][3][crow][g * 8 + cu] + b1v[g];
      const float cn = sigf(gv[1]) * c1 + sigf(gv[0]) * tanhf_fast(gv[2]);
      const float hn = sigf(gv[3]) * tanhf_fast(cn);
      c1 = cn;
      smH[1][crow][cu] = (f16)hn;
      st_f32g(&out[(size_t)(rs + crow) * (T_ * H_) + (size_t)t * H_ + ub + cu], hn);
      if (e == T_) { st_f32g(&outh[(size_t)B_ * H_ + cell], hn); st_f32g(&outc[(size_t)B_ * H_ + cell], cn); }
    }
    __syncthreads();

    // publish h slices: uncached 8B stores by wave0 (layer0) / wave1 (layer1)
    if (A0 && p == 0) {
      const int row = lane >> 1, half = lane & 1;
      unsigned long long v = *(const unsigned long long*)&smH[0][row][half * 4];
      st_u64g((unsigned long long*)(h0buf + (size_t)(e & 1) * (B_ * H_)
                                    + (size_t)(rs + row) * H_ + ub + half * 4), v);
    }
    if (A1 && p == 1) {
      const int row = lane >> 1, half = lane & 1;
      unsigned long long v = *(const unsigned long long*)&smH[1][row][half * 4];
      st_u64g((unsigned long long*)(h1buf + (size_t)((e - 1) & 1) * (B_ * H_)
                                    + (size_t)(rs + row) * H_ + ub + half * 4), v);
    }
  };

  for (int e = 0; e <= T_; ++e) {
    if (e > 0 && p == 0) {
      // wave0 polls all 128 pod flags with one uncached 8B load per lane
      const unsigned long long* fp = (const unsigned long long*)podflags;
      for (;;) {
        unsigned long long v = ld_u64g(&fp[lane]);
        const bool ok = ((unsigned)v >= (unsigned)e) && ((unsigned)(v >> 32) >= (unsigned)e);
        if (__ballot(ok) == ~0ull) break;
        __builtin_amdgcn_s_sleep(1);
      }
    }
    __syncthreads();
    __builtin_amdgcn_fence(__ATOMIC_ACQUIRE, "agent");   // inv only (nothing dirty)

    if (e == 0)            body(BC<true>{},  BC<false>{}, 0);
    else if (e == T_)      body(BC<false>{}, BC<true>{},  T_);
    else                   body(BC<true>{},  BC<true>{},  e);

    asm volatile("s_waitcnt vmcnt(0)" ::: "memory");  // drain uncached stores
    __syncthreads();
    if (tid == 0) st_u32g(&podflags[slot], (unsigned)(e + 1));
  }
}

// ---------------------------------------------------------------------------
extern "C" void kernel_launch(void* const* d_in, const int* in_sizes, int n_in,
                              void* d_out, int out_size, void* d_ws, size_t ws_size,
                              hipStream_t stream)
{
  const float* x    = (const float*)d_in[0];
  const float* h    = (const float*)d_in[1];
  const float* c    = (const float*)d_in[2];
  const float* Wih0 = (const float*)d_in[3];
  const float* Whh0 = (const float*)d_in[4];
  const float* bih0 = (const float*)d_in[5];
  const float* bhh0 = (const float*)d_in[6];
  const float* Wih1 = (const float*)d_in[7];
  const float* Whh1 = (const float*)d_in[8];
  const float* bih1 = (const float*)d_in[9];
  const float* bhh1 = (const float*)d_in[10];

  char* w = (char*)d_ws;
  size_t off = 0;
  auto carve = [&](size_t bytes) -> char* {
    char* p = w + off;
    off = (off + bytes + 255) & ~(size_t)255;
    return p;
  };
  f16*   pre0T = (f16*)  carve((size_t)T_ * B_ * FH_ * 2);
  f16*   xT    = (f16*)  carve((size_t)T_ * B_ * N_ * 2);
  f16*   wih0  = (f16*)  carve((size_t)FH_ * N_ * 2);
  f16*   whh0  = (f16*)  carve((size_t)FH_ * H_ * 2);
  f16*   wih1  = (f16*)  carve((size_t)FH_ * H_ * 2);
  f16*   whh1  = (f16*)  carve((size_t)FH_ * H_ * 2);
  float* bias0 = (float*)carve((size_t)FH_ * 4);
  float* bias1 = (float*)carve((size_t)FH_ * 4);
  f16*   hinit = (f16*)  carve((size_t)2 * B_ * H_ * 2);
  f16*   h0buf = (f16*)  carve((size_t)2 * B_ * H_ * 2);
  f16*   h1buf = (f16*)  carve((size_t)2 * B_ * H_ * 2);
  unsigned* flags = (unsigned*)carve(NWG_SEQ * 4);
  if (off > ws_size) return;

  init_all<<<2048, 256, 0, stream>>>(x, h, Wih0, bih0, bhh0, Whh0, Wih1, Whh1, bih1, bhh1,
                                     xT, wih0, whh0, wih1, whh1, bias0, bias1, hinit, flags);
  gemm_pre0<<<4096, 256, 0, stream>>>(xT, wih0, bias0, pre0T);
  lstm_seq<<<NWG_SEQ, 256, 0, stream>>>(pre0T, whh0, wih1, whh1, bias1, hinit, (const float*)c,
                                        h0buf, h1buf, (float*)d_out, flags);
}